// Round 7
// baseline (154.284 us; speedup 1.0000x reference)
//
#include <hip/hip_runtime.h>
#include <hip/hip_bf16.h>

typedef float f32x4 __attribute__((ext_vector_type(4)));
typedef __bf16 bf16x8 __attribute__((ext_vector_type(8)));

#define N 8192
#define CH 256
#define NJC 4            // j-chunks
#define JCW (N / NJC)    // 2048 j per chunk
#define JT 128           // j per tile
#define NT (JCW / JT)    // 16 tiles per chunk
#define BM 64            // rows per block

// ---- workspace layout (bytes) ----
static constexpr size_t OFF_P1 = 0;
static constexpr size_t OFF_P2 = 32768;
static constexpr size_t OFF_T1 = 65536;
static constexpr size_t OFF_T2 = 66560;
static constexpr size_t OFF_F1 = 67584;
static constexpr size_t OFF_F2 = OFF_F1 + (size_t)N * 4;
static constexpr size_t OFF_XT = 262144;                       // packed B, 4 MB
static constexpr size_t OFF_SP = OFF_XT + (size_t)CH * N * 2;  // 4x8192 f32
static constexpr size_t OFF_PV = OFF_SP + (size_t)NJC * N * 4; // 3x8 MB

// K1a: partial t-vectors over h-slices of 8.
__global__ __launch_bounds__(256) void k1a(
    const float* __restrict__ W, const float* __restrict__ w1,
    const float* __restrict__ w2, float* __restrict__ p1, float* __restrict__ p2)
{
    int b = blockIdx.x, c = threadIdx.x;
    float a1 = 0.f, a2 = 0.f;
#pragma unroll
    for (int hh = 0; hh < 8; ++hh) {
        int h = b * 8 + hh;
        float wv = W[h * CH + c];
        a1 = __builtin_fmaf(w1[h], wv, a1);
        a2 = __builtin_fmaf(w2[h], wv, a2);
    }
    p1[b * CH + c] = a1;
    p2[b * CH + c] = a2;
}

// K1b: fold 32 partials -> t1,t2.
__global__ __launch_bounds__(256) void k1b(
    const float* __restrict__ p1, const float* __restrict__ p2,
    float* __restrict__ t1, float* __restrict__ t2)
{
    int c = threadIdx.x;
    float a1 = 0.f, a2 = 0.f;
#pragma unroll 8
    for (int b = 0; b < 32; ++b) { a1 += p1[b * CH + c]; a2 += p2[b * CH + c]; }
    t1[c] = a1;
    t2[c] = a2;
}

// KTF: fused pack + f1/f2. inlayer [N][CH] f32 -> xtp fragment-packed bf16 and
// per-row dots f1,f2 (wave-reduce; one wave owns one row per pass).
// xtp unit u = (ct*256 + js32)*64 + lane holds 8 bf16:
//   value[e] = X[js32*32 + (lane>>4)*8 + e][ct*16 + (lane&15)]
__global__ __launch_bounds__(256) void ktf(
    const float* __restrict__ x, const float* __restrict__ t1,
    const float* __restrict__ t2, const float* __restrict__ b1,
    const float* __restrict__ b2, unsigned short* __restrict__ xtp,
    float* __restrict__ f1, float* __restrict__ f2)
{
    __shared__ unsigned short tile[32][264];     // +8 pad
    int js32 = blockIdx.x;
    int jb = js32 * 32;
    int t = threadIdx.x;
    int lane = t & 63;
    int wv = t >> 6;
    const float4* t1v = (const float4*)t1;
    const float4* t2v = (const float4*)t2;
    float4 ta = t1v[lane], tb = t2v[lane];
    float bb1 = b1[0], bb2 = b2[0];
#pragma unroll
    for (int it = 0; it < 8; ++it) {
        int jr = it * 4 + wv;
        float4 v = *(const float4*)(x + (size_t)(jb + jr) * CH + lane * 4);
        __hip_bfloat16 h0 = __float2bfloat16(v.x);
        __hip_bfloat16 h1 = __float2bfloat16(v.y);
        __hip_bfloat16 h2 = __float2bfloat16(v.z);
        __hip_bfloat16 h3 = __float2bfloat16(v.w);
        tile[jr][lane * 4 + 0] = *(unsigned short*)&h0;
        tile[jr][lane * 4 + 1] = *(unsigned short*)&h1;
        tile[jr][lane * 4 + 2] = *(unsigned short*)&h2;
        tile[jr][lane * 4 + 3] = *(unsigned short*)&h3;
        float d1 = v.x * ta.x + v.y * ta.y + v.z * ta.z + v.w * ta.w;
        float d2 = v.x * tb.x + v.y * tb.y + v.z * tb.z + v.w * tb.w;
#pragma unroll
        for (int off = 32; off; off >>= 1) {
            d1 += __shfl_down(d1, off);
            d2 += __shfl_down(d2, off);
        }
        if (lane == 0) { f1[jb + jr] = d1 + bb1; f2[jb + jr] = d2 + bb2; }
    }
    __syncthreads();
    int r = lane & 15, q = lane >> 4;
#pragma unroll
    for (int pass = 0; pass < 4; ++pass) {
        int ct = pass * 4 + wv;
        unsigned short vs[8];
#pragma unroll
        for (int e = 0; e < 8; ++e) vs[e] = tile[q * 8 + e][ct * 16 + r];
        size_t u = ((size_t)ct * 256 + js32) * 64 + lane;
        *(ulonglong2*)(xtp + u * 8) = *(ulonglong2*)vs;
    }
}

// Raw barrier: LDS visibility only; global prefetches stay in flight (T4).
#define BAR() { asm volatile("s_waitcnt lgkmcnt(0)" ::: "memory"); \
                __builtin_amdgcn_s_barrier(); }

// K34 v7: BM=64 rows x 2048-j chunk, 512 threads (8 waves = 8 ch-groups).
// B double-use named register set: per tile, consume B(t) (WAR pins issue
// order) -> reload B(t+1) -> adj prefetch A(t+2) -> EXPW A(t+1). Counted
// vmcnt keeps adj ~1.5 tiles in flight; B hides under EXPW+BAR.
__global__ __launch_bounds__(512, 4) void k34_fused(
    const int* __restrict__ adj, const float* __restrict__ f1,
    const float* __restrict__ f2, const unsigned short* __restrict__ xtp,
    float* __restrict__ pv0, float* __restrict__ pvx, float* __restrict__ s_part)
{
    __shared__ __align__(16) unsigned short P[2][BM * JT];   // 2 x 16 KB
    __shared__ __align__(16) float f2s[JCW];                 // 8 KB

    const int tid = threadIdx.x;
    const int lane = tid & 63;
    const int w = tid >> 6;              // ch-group 0..7
    const int r = lane & 15, q = lane >> 4;
    const int bid = blockIdx.x;
    const int jc = bid & 3;              // j-chunk (XCD L2 affinity)
    const int rb = (bid >> 2) * BM;
    const int jbase = jc * JCW;

    // producer role: row = tid>>3 (0..63), 16 j's at (tid&7)*16
    const int prow = tid >> 3;
    const int pjo = (tid & 7) * 16;
    const float f1r = f1[rb + prow];
    const int* aptr = adj + (size_t)(rb + prow) * N + jbase + pjo;
    const int s0i = (tid & 7) * 2;
    const int wu0 = prow * 16 + (s0i ^ (prow & 7));
    const int wu1 = prow * 16 + ((s0i + 1) ^ (prow & 7));

    // consumer role: wave w covers cts {w*2, w*2+1}
    const unsigned short* xb0 = xtp + (((size_t)(w * 2) * 256 + jc * 64) * 64 + lane) * 8;
    const unsigned short* xb1 = xtp + (((size_t)(w * 2 + 1) * 256 + jc * 64) * 64 + lane) * 8;

    f32x4 acc[4][2];
#pragma unroll
    for (int mt = 0; mt < 4; ++mt)
#pragma unroll
        for (int nt = 0; nt < 2; ++nt) acc[mt][nt] = (f32x4){0.f, 0.f, 0.f, 0.f};
    float s_acc = 0.f;

    int4 RA0, RA1, RA2, RA3, RB0, RB1, RB2, RB3;
    bf16x8 Bv0, Bv1, Bv2, Bv3, Bv4, Bv5, Bv6, Bv7;

#define LOAD_A(R0, R1, R2, R3, t)                                   \
    { const int4* p_ = (const int4*)(aptr + (size_t)(t) * JT);      \
      R0 = p_[0]; R1 = p_[1]; R2 = p_[2]; R3 = p_[3]; }
#define LOAD_B(tt)                                                  \
    { Bv0 = *(const bf16x8*)(xb0 + ((size_t)((tt) * 4 + 0) * 64) * 8); \
      Bv1 = *(const bf16x8*)(xb0 + ((size_t)((tt) * 4 + 1) * 64) * 8); \
      Bv2 = *(const bf16x8*)(xb0 + ((size_t)((tt) * 4 + 2) * 64) * 8); \
      Bv3 = *(const bf16x8*)(xb0 + ((size_t)((tt) * 4 + 3) * 64) * 8); \
      Bv4 = *(const bf16x8*)(xb1 + ((size_t)((tt) * 4 + 0) * 64) * 8); \
      Bv5 = *(const bf16x8*)(xb1 + ((size_t)((tt) * 4 + 1) * 64) * 8); \
      Bv6 = *(const bf16x8*)(xb1 + ((size_t)((tt) * 4 + 2) * 64) * 8); \
      Bv7 = *(const bf16x8*)(xb1 + ((size_t)((tt) * 4 + 3) * 64) * 8); }
#define EXPW(R0, R1, R2, R3, buf, tt)                               \
    { float4 g0 = *(const float4*)(&f2s[(tt) * JT + pjo]);          \
      float4 g1 = *(const float4*)(&f2s[(tt) * JT + pjo + 4]);      \
      float4 g2 = *(const float4*)(&f2s[(tt) * JT + pjo + 8]);      \
      float4 g3 = *(const float4*)(&f2s[(tt) * JT + pjo + 12]);     \
      int av[16] = {R0.x, R0.y, R0.z, R0.w, R1.x, R1.y, R1.z, R1.w, \
                    R2.x, R2.y, R2.z, R2.w, R3.x, R3.y, R3.z, R3.w};\
      float gv[16] = {g0.x, g0.y, g0.z, g0.w, g1.x, g1.y, g1.z, g1.w,\
                      g2.x, g2.y, g2.z, g2.w, g3.x, g3.y, g3.z, g3.w};\
      bf16x8 pk0, pk1;                                              \
      _Pragma("unroll")                                             \
      for (int e = 0; e < 16; ++e) {                                \
          float t_ = f1r + gv[e];                                   \
          t_ = fmaxf(t_, 0.01f * t_);                               \
          float p_ = (av[e] > 0) ? __expf(t_) : 0.f;                \
          s_acc += p_;                                              \
          if (e < 8) pk0[e] = (__bf16)p_; else pk1[e - 8] = (__bf16)p_; \
      }                                                             \
      *reinterpret_cast<bf16x8*>(&P[buf][(size_t)wu0 * 8]) = pk0;   \
      *reinterpret_cast<bf16x8*>(&P[buf][(size_t)wu1 * 8]) = pk1; }
#define MFMA_TILE(buf)                                              \
    { _Pragma("unroll")                                             \
      for (int kk = 0; kk < 4; ++kk) {                              \
          bf16x8 B0 = (kk == 0) ? Bv0 : (kk == 1) ? Bv1 : (kk == 2) ? Bv2 : Bv3; \
          bf16x8 B1 = (kk == 0) ? Bv4 : (kk == 1) ? Bv5 : (kk == 2) ? Bv6 : Bv7; \
          _Pragma("unroll")                                         \
          for (int mt = 0; mt < 4; ++mt) {                          \
              int u_ = (mt * 16 + r) * 16 + ((kk * 4 + q) ^ (r & 7)); \
              bf16x8 A = *(const bf16x8*)(&P[buf][(size_t)u_ * 8]); \
              acc[mt][0] = __builtin_amdgcn_mfma_f32_16x16x32_bf16(A, B0, acc[mt][0], 0, 0, 0); \
              acc[mt][1] = __builtin_amdgcn_mfma_f32_16x16x32_bf16(A, B1, acc[mt][1], 0, 0, 0); \
          }                                                         \
      } }

    // prologue
    LOAD_A(RA0, RA1, RA2, RA3, 0);
    LOAD_A(RB0, RB1, RB2, RB3, 1);
    LOAD_B(0);
    *(float4*)(&f2s[tid * 4]) = *(const float4*)(f2 + jbase + tid * 4);
    __syncthreads();                      // f2s staged (full drain once)
    EXPW(RA0, RA1, RA2, RA3, 0, 0);
    BAR();

    for (int t = 0; t < NT; t += 2) {
        // even sub-iter: consume P[0] + B(t); refill B(t+1); prefetch A(t+2)
        MFMA_TILE(0);
        LOAD_B(t + 1);
        if (t + 2 < NT) LOAD_A(RA0, RA1, RA2, RA3, t + 2);
        EXPW(RB0, RB1, RB2, RB3, 1, t + 1);
        BAR();
        // odd sub-iter: consume P[1] + B(t+1); refill B(t+2); prefetch A(t+3)
        MFMA_TILE(1);
        if (t + 2 < NT) LOAD_B(t + 2);
        if (t + 3 < NT) LOAD_A(RB0, RB1, RB2, RB3, t + 3);
        if (t + 2 < NT) EXPW(RA0, RA1, RA2, RA3, 0, t + 2);
        BAR();
    }

    // row-sum partial: 8 threads per row (consecutive lanes)
    s_acc += __shfl_xor(s_acc, 1);
    s_acc += __shfl_xor(s_acc, 2);
    s_acc += __shfl_xor(s_acc, 4);
    if ((lane & 7) == 0) s_part[jc * N + rb + prow] = s_acc;

    // write PV partial. D layout: col = lane&15, row = (lane>>4)*4 + reg
    float* dst = (jc == 0) ? pv0 : (pvx + (size_t)(jc - 1) * N * CH);
#pragma unroll
    for (int mt = 0; mt < 4; ++mt)
#pragma unroll
        for (int nt = 0; nt < 2; ++nt)
#pragma unroll
            for (int reg = 0; reg < 4; ++reg) {
                int row = rb + mt * 16 + q * 4 + reg;
                int col = w * 32 + nt * 16 + r;
                dst[(size_t)row * CH + col] = acc[mt][nt][reg];
            }
#undef LOAD_A
#undef LOAD_B
#undef EXPW
#undef MFMA_TILE
}

// K5: out[i][c] = (sum_k pv_k) * inv(sum_k s_k). pv0 lives in d_out.
__global__ __launch_bounds__(256) void k5_reduce(
    const float* __restrict__ pvx, const float* __restrict__ s_part,
    float* __restrict__ out)
{
    int g = blockIdx.x * 256 + threadIdx.x;      // float4 index
    int row = g >> 6;
    float s = s_part[row] + s_part[N + row] + s_part[2 * N + row] + s_part[3 * N + row];
    float inv = (s != 0.f) ? 1.0f / s : 0.f;
    float4* out4 = (float4*)out;
    const float4* p1 = (const float4*)pvx;
    const float4* p2 = p1 + (size_t)N * CH / 4;
    const float4* p3 = p2 + (size_t)N * CH / 4;
    float4 v = out4[g];
    float4 a = p1[g], b = p2[g], c = p3[g];
    v.x = (v.x + a.x + b.x + c.x) * inv;
    v.y = (v.y + a.y + b.y + c.y) * inv;
    v.z = (v.z + a.z + b.z + c.z) * inv;
    v.w = (v.w + a.w + b.w + c.w) * inv;
    out4[g] = v;
}

extern "C" void kernel_launch(void* const* d_in, const int* in_sizes, int n_in,
                              void* d_out, int out_size, void* d_ws, size_t ws_size,
                              hipStream_t stream)
{
    const float* inlayer = (const float*)d_in[0];
    const int*   adj     = (const int*)d_in[1];
    const float* W       = (const float*)d_in[2];
    const float* w1      = (const float*)d_in[3];
    const float* b1      = (const float*)d_in[4];
    const float* w2      = (const float*)d_in[5];
    const float* b2      = (const float*)d_in[6];
    float* out = (float*)d_out;

    char* ws = (char*)d_ws;
    float* p1 = (float*)(ws + OFF_P1);
    float* p2 = (float*)(ws + OFF_P2);
    float* t1 = (float*)(ws + OFF_T1);
    float* t2 = (float*)(ws + OFF_T2);
    float* f1 = (float*)(ws + OFF_F1);
    float* f2 = (float*)(ws + OFF_F2);
    unsigned short* xtp = (unsigned short*)(ws + OFF_XT);
    float* s_part = (float*)(ws + OFF_SP);
    float* pvx = (float*)(ws + OFF_PV);

    k1a<<<dim3(32), dim3(256), 0, stream>>>(W, w1, w2, p1, p2);
    k1b<<<dim3(1), dim3(256), 0, stream>>>(p1, p2, t1, t2);
    ktf<<<dim3(N / 32), dim3(256), 0, stream>>>(
        inlayer, t1, t2, b1, b2, xtp, f1, f2);
    k34_fused<<<dim3((N / BM) * NJC), dim3(512), 0, stream>>>(
        adj, f1, f2, xtp, out, pvx, s_part);
    k5_reduce<<<dim3(N * CH / 4 / 256), dim3(256), 0, stream>>>(pvx, s_part, out);
}

// Round 8
// 136.036 us; speedup vs baseline: 1.1341x; 1.1341x over previous
//
#include <hip/hip_runtime.h>
#include <hip/hip_bf16.h>

typedef float f32x4 __attribute__((ext_vector_type(4)));
typedef __bf16 bf16x8 __attribute__((ext_vector_type(8)));

#define N 8192
#define CH 256
#define NJC 4            // j-chunks
#define JCW (N / NJC)    // 2048 j per chunk
#define JT 128           // j per tile
#define NT (JCW / JT)    // 16 tiles per chunk
#define BM 64            // rows per block

// ---- workspace layout (bytes) ----
static constexpr size_t OFF_P1 = 0;
static constexpr size_t OFF_P2 = 32768;
static constexpr size_t OFF_T1 = 65536;
static constexpr size_t OFF_T2 = 66560;
static constexpr size_t OFF_F1 = 67584;
static constexpr size_t OFF_F2 = OFF_F1 + (size_t)N * 4;
static constexpr size_t OFF_XT = 262144;                       // packed B, 4 MB
static constexpr size_t OFF_SP = OFF_XT + (size_t)CH * N * 2;  // 4x8192 f32
static constexpr size_t OFF_PV = OFF_SP + (size_t)NJC * N * 4; // 3x8 MB
static constexpr size_t OFF_MK = OFF_PV + (size_t)3 * N * CH * 4; // 8 MB mask

// K0: compress adj [N][N] int32 -> bitmask (1 bit per entry). Pure streaming.
// word w (u32) covers j = (w*32..w*32+31) within row-major flattening.
__global__ __launch_bounds__(256) void k0_mask(
    const int4* __restrict__ adj4, unsigned* __restrict__ mask)
{
    const int nw = N * N / 32;                   // 2M u32 words
    int stride = gridDim.x * 256;
    for (int w = blockIdx.x * 256 + threadIdx.x; w < nw; w += stride) {
        const int4* p = adj4 + (size_t)w * 8;
        unsigned m = 0;
#pragma unroll
        for (int u = 0; u < 8; ++u) {
            int4 v = p[u];
            m |= (unsigned)(v.x > 0) << (u * 4 + 0);
            m |= (unsigned)(v.y > 0) << (u * 4 + 1);
            m |= (unsigned)(v.z > 0) << (u * 4 + 2);
            m |= (unsigned)(v.w > 0) << (u * 4 + 3);
        }
        mask[w] = m;
    }
}

// K1a: partial t-vectors over h-slices of 8.
__global__ __launch_bounds__(256) void k1a(
    const float* __restrict__ W, const float* __restrict__ w1,
    const float* __restrict__ w2, float* __restrict__ p1, float* __restrict__ p2)
{
    int b = blockIdx.x, c = threadIdx.x;
    float a1 = 0.f, a2 = 0.f;
#pragma unroll
    for (int hh = 0; hh < 8; ++hh) {
        int h = b * 8 + hh;
        float wv = W[h * CH + c];
        a1 = __builtin_fmaf(w1[h], wv, a1);
        a2 = __builtin_fmaf(w2[h], wv, a2);
    }
    p1[b * CH + c] = a1;
    p2[b * CH + c] = a2;
}

// K1b: fold 32 partials -> t1,t2.
__global__ __launch_bounds__(256) void k1b(
    const float* __restrict__ p1, const float* __restrict__ p2,
    float* __restrict__ t1, float* __restrict__ t2)
{
    int c = threadIdx.x;
    float a1 = 0.f, a2 = 0.f;
#pragma unroll 8
    for (int b = 0; b < 32; ++b) { a1 += p1[b * CH + c]; a2 += p2[b * CH + c]; }
    t1[c] = a1;
    t2[c] = a2;
}

// KTF: fused pack + f1/f2. inlayer [N][CH] f32 -> xtp fragment-packed bf16 and
// per-row dots f1,f2.
__global__ __launch_bounds__(256) void ktf(
    const float* __restrict__ x, const float* __restrict__ t1,
    const float* __restrict__ t2, const float* __restrict__ b1,
    const float* __restrict__ b2, unsigned short* __restrict__ xtp,
    float* __restrict__ f1, float* __restrict__ f2)
{
    __shared__ unsigned short tile[32][264];     // +8 pad
    int js32 = blockIdx.x;
    int jb = js32 * 32;
    int t = threadIdx.x;
    int lane = t & 63;
    int wv = t >> 6;
    const float4* t1v = (const float4*)t1;
    const float4* t2v = (const float4*)t2;
    float4 ta = t1v[lane], tb = t2v[lane];
    float bb1 = b1[0], bb2 = b2[0];
#pragma unroll
    for (int it = 0; it < 8; ++it) {
        int jr = it * 4 + wv;
        float4 v = *(const float4*)(x + (size_t)(jb + jr) * CH + lane * 4);
        __hip_bfloat16 h0 = __float2bfloat16(v.x);
        __hip_bfloat16 h1 = __float2bfloat16(v.y);
        __hip_bfloat16 h2 = __float2bfloat16(v.z);
        __hip_bfloat16 h3 = __float2bfloat16(v.w);
        tile[jr][lane * 4 + 0] = *(unsigned short*)&h0;
        tile[jr][lane * 4 + 1] = *(unsigned short*)&h1;
        tile[jr][lane * 4 + 2] = *(unsigned short*)&h2;
        tile[jr][lane * 4 + 3] = *(unsigned short*)&h3;
        float d1 = v.x * ta.x + v.y * ta.y + v.z * ta.z + v.w * ta.w;
        float d2 = v.x * tb.x + v.y * tb.y + v.z * tb.z + v.w * tb.w;
#pragma unroll
        for (int off = 32; off; off >>= 1) {
            d1 += __shfl_down(d1, off);
            d2 += __shfl_down(d2, off);
        }
        if (lane == 0) { f1[jb + jr] = d1 + bb1; f2[jb + jr] = d2 + bb2; }
    }
    __syncthreads();
    int r = lane & 15, q = lane >> 4;
#pragma unroll
    for (int pass = 0; pass < 4; ++pass) {
        int ct = pass * 4 + wv;
        unsigned short vs[8];
#pragma unroll
        for (int e = 0; e < 8; ++e) vs[e] = tile[q * 8 + e][ct * 16 + r];
        size_t u = ((size_t)ct * 256 + js32) * 64 + lane;
        *(ulonglong2*)(xtp + u * 8) = *(ulonglong2*)vs;
    }
}

// Raw barrier: LDS visibility only; global loads stay in flight.
#define BAR() { asm volatile("s_waitcnt lgkmcnt(0)" ::: "memory"); \
                __builtin_amdgcn_s_barrier(); }

// K34 v8 = v6 structure with mask input (L2-resident) instead of adj (HBM).
// BM=64 rows x 2048-j chunk, 512 threads (8 waves = 8 ch-groups of 32).
// B fragment-packed (compiler-scheduled loads inside MFMA tile, v6-style).
// P double-buffered LDS, XOR-swizzled unit = row*16 + (slot ^ (row&7)).
__global__ __launch_bounds__(512, 4) void k34_fused(
    const unsigned short* __restrict__ mask16, const float* __restrict__ f1,
    const float* __restrict__ f2, const unsigned short* __restrict__ xtp,
    float* __restrict__ pv0, float* __restrict__ pvx, float* __restrict__ s_part)
{
    __shared__ __align__(16) unsigned short P[2][BM * JT];   // 2 x 16 KB
    __shared__ __align__(16) float f2s[JCW];                 // 8 KB

    const int tid = threadIdx.x;
    const int lane = tid & 63;
    const int w = tid >> 6;              // ch-group 0..7
    const int r = lane & 15, q = lane >> 4;
    const int bid = blockIdx.x;
    const int jc = bid & 3;              // j-chunk (XCD L2 affinity)
    const int rb = (bid >> 2) * BM;
    const int jbase = jc * JCW;

    // producer role: row = tid>>3 (0..63), 16 j's at (tid&7)*16
    const int prow = tid >> 3;
    const int pjo = (tid & 7) * 16;
    const float f1r = f1[rb + prow];
    // mask ushort stream for this thread: one ushort per tile, stride 8 ushorts
    const unsigned short* mrow = mask16 + (size_t)(rb + prow) * 512 + jc * 128 + (tid & 7);
    const int s0i = (tid & 7) * 2;
    const int wu0 = prow * 16 + (s0i ^ (prow & 7));
    const int wu1 = prow * 16 + ((s0i + 1) ^ (prow & 7));

    // consumer role: wave w covers cts {w*2, w*2+1}
    const unsigned short* xb0 = xtp + (((size_t)(w * 2) * 256 + jc * 64) * 64 + lane) * 8;
    const unsigned short* xb1 = xtp + (((size_t)(w * 2 + 1) * 256 + jc * 64) * 64 + lane) * 8;

    f32x4 acc[4][2];
#pragma unroll
    for (int mt = 0; mt < 4; ++mt)
#pragma unroll
        for (int nt = 0; nt < 2; ++nt) acc[mt][nt] = (f32x4){0.f, 0.f, 0.f, 0.f};
    float s_acc = 0.f;

    unsigned MA, MB;

#define EXPW(mreg, buf, tt)                                         \
    { float4 g0 = *(const float4*)(&f2s[(tt) * JT + pjo]);          \
      float4 g1 = *(const float4*)(&f2s[(tt) * JT + pjo + 4]);      \
      float4 g2 = *(const float4*)(&f2s[(tt) * JT + pjo + 8]);      \
      float4 g3 = *(const float4*)(&f2s[(tt) * JT + pjo + 12]);     \
      float gv[16] = {g0.x, g0.y, g0.z, g0.w, g1.x, g1.y, g1.z, g1.w,\
                      g2.x, g2.y, g2.z, g2.w, g3.x, g3.y, g3.z, g3.w};\
      bf16x8 pk0, pk1;                                              \
      _Pragma("unroll")                                             \
      for (int e = 0; e < 16; ++e) {                                \
          float t_ = f1r + gv[e];                                   \
          t_ = fmaxf(t_, 0.01f * t_);                               \
          float p_ = ((mreg >> e) & 1u) ? __expf(t_) : 0.f;         \
          s_acc += p_;                                              \
          if (e < 8) pk0[e] = (__bf16)p_; else pk1[e - 8] = (__bf16)p_; \
      }                                                             \
      *reinterpret_cast<bf16x8*>(&P[buf][(size_t)wu0 * 8]) = pk0;   \
      *reinterpret_cast<bf16x8*>(&P[buf][(size_t)wu1 * 8]) = pk1; }
#define MFMA_TILE(tt, buf)                                          \
    { _Pragma("unroll")                                             \
      for (int kk = 0; kk < 4; ++kk) {                              \
          bf16x8 B0 = *(const bf16x8*)(xb0 + ((size_t)((tt) * 4 + kk) * 64) * 8); \
          bf16x8 B1 = *(const bf16x8*)(xb1 + ((size_t)((tt) * 4 + kk) * 64) * 8); \
          _Pragma("unroll")                                         \
          for (int mt = 0; mt < 4; ++mt) {                          \
              int u_ = (mt * 16 + r) * 16 + ((kk * 4 + q) ^ (r & 7)); \
              bf16x8 A = *(const bf16x8*)(&P[buf][(size_t)u_ * 8]); \
              acc[mt][0] = __builtin_amdgcn_mfma_f32_16x16x32_bf16(A, B0, acc[mt][0], 0, 0, 0); \
              acc[mt][1] = __builtin_amdgcn_mfma_f32_16x16x32_bf16(A, B1, acc[mt][1], 0, 0, 0); \
          }                                                         \
      } }

    // prologue
    MA = mrow[0];
    MB = mrow[8];
    *(float4*)(&f2s[tid * 4]) = *(const float4*)(f2 + jbase + tid * 4);
    __syncthreads();                      // f2s staged (full drain once)
    EXPW(MA, 0, 0);
    BAR();

    for (int t = 0; t < NT; t += 2) {
        if (t + 2 < NT) MA = mrow[(t + 2) * 8];
        MFMA_TILE(t, 0);
        EXPW(MB, 1, t + 1);
        BAR();
        if (t + 3 < NT) MB = mrow[(t + 3) * 8];
        MFMA_TILE(t + 1, 1);
        if (t + 2 < NT) EXPW(MA, 0, t + 2);
        BAR();
    }

    // row-sum partial: 8 threads per row (consecutive lanes)
    s_acc += __shfl_xor(s_acc, 1);
    s_acc += __shfl_xor(s_acc, 2);
    s_acc += __shfl_xor(s_acc, 4);
    if ((lane & 7) == 0) s_part[jc * N + rb + prow] = s_acc;

    // write PV partial. D layout: col = lane&15, row = (lane>>4)*4 + reg
    float* dst = (jc == 0) ? pv0 : (pvx + (size_t)(jc - 1) * N * CH);
#pragma unroll
    for (int mt = 0; mt < 4; ++mt)
#pragma unroll
        for (int nt = 0; nt < 2; ++nt)
#pragma unroll
            for (int reg = 0; reg < 4; ++reg) {
                int row = rb + mt * 16 + q * 4 + reg;
                int col = w * 32 + nt * 16 + r;
                dst[(size_t)row * CH + col] = acc[mt][nt][reg];
            }
#undef EXPW
#undef MFMA_TILE
}

// K5: out[i][c] = (sum_k pv_k) * inv(sum_k s_k). pv0 lives in d_out.
__global__ __launch_bounds__(256) void k5_reduce(
    const float* __restrict__ pvx, const float* __restrict__ s_part,
    float* __restrict__ out)
{
    int g = blockIdx.x * 256 + threadIdx.x;      // float4 index
    int row = g >> 6;
    float s = s_part[row] + s_part[N + row] + s_part[2 * N + row] + s_part[3 * N + row];
    float inv = (s != 0.f) ? 1.0f / s : 0.f;
    float4* out4 = (float4*)out;
    const float4* p1 = (const float4*)pvx;
    const float4* p2 = p1 + (size_t)N * CH / 4;
    const float4* p3 = p2 + (size_t)N * CH / 4;
    float4 v = out4[g];
    float4 a = p1[g], b = p2[g], c = p3[g];
    v.x = (v.x + a.x + b.x + c.x) * inv;
    v.y = (v.y + a.y + b.y + c.y) * inv;
    v.z = (v.z + a.z + b.z + c.z) * inv;
    v.w = (v.w + a.w + b.w + c.w) * inv;
    out4[g] = v;
}

extern "C" void kernel_launch(void* const* d_in, const int* in_sizes, int n_in,
                              void* d_out, int out_size, void* d_ws, size_t ws_size,
                              hipStream_t stream)
{
    const float* inlayer = (const float*)d_in[0];
    const int*   adj     = (const int*)d_in[1];
    const float* W       = (const float*)d_in[2];
    const float* w1      = (const float*)d_in[3];
    const float* b1      = (const float*)d_in[4];
    const float* w2      = (const float*)d_in[5];
    const float* b2      = (const float*)d_in[6];
    float* out = (float*)d_out;

    char* ws = (char*)d_ws;
    float* p1 = (float*)(ws + OFF_P1);
    float* p2 = (float*)(ws + OFF_P2);
    float* t1 = (float*)(ws + OFF_T1);
    float* t2 = (float*)(ws + OFF_T2);
    float* f1 = (float*)(ws + OFF_F1);
    float* f2 = (float*)(ws + OFF_F2);
    unsigned short* xtp = (unsigned short*)(ws + OFF_XT);
    float* s_part = (float*)(ws + OFF_SP);
    float* pvx = (float*)(ws + OFF_PV);
    unsigned* mask = (unsigned*)(ws + OFF_MK);

    k0_mask<<<dim3(2048), dim3(256), 0, stream>>>((const int4*)adj, mask);
    k1a<<<dim3(32), dim3(256), 0, stream>>>(W, w1, w2, p1, p2);
    k1b<<<dim3(1), dim3(256), 0, stream>>>(p1, p2, t1, t2);
    ktf<<<dim3(N / 32), dim3(256), 0, stream>>>(
        inlayer, t1, t2, b1, b2, xtp, f1, f2);
    k34_fused<<<dim3((N / BM) * NJC), dim3(512), 0, stream>>>(
        (const unsigned short*)mask, f1, f2, xtp, out, pvx, s_part);
    k5_reduce<<<dim3(N * CH / 4 / 256), dim3(256), 0, stream>>>(pvx, s_part, out);
}

// Round 9
// 101.753 us; speedup vs baseline: 1.5163x; 1.3369x over previous
//
#include <hip/hip_runtime.h>
#include <hip/hip_bf16.h>

typedef float f32x4 __attribute__((ext_vector_type(4)));
typedef __bf16 bf16x8 __attribute__((ext_vector_type(8)));

#define N 8192
#define CH 256
#define NJC 2            // j-chunks
#define JCW (N / NJC)    // 4096 j per chunk
#define JT 128           // j per tile
#define NT (JCW / JT)    // 32 tiles per chunk
#define BM 64            // rows per block

// ---- workspace layout (bytes) ----
static constexpr size_t OFF_P1 = 0;
static constexpr size_t OFF_P2 = 32768;
static constexpr size_t OFF_T1 = 65536;
static constexpr size_t OFF_T2 = 66560;
static constexpr size_t OFF_F1 = 67584;
static constexpr size_t OFF_F2 = OFF_F1 + (size_t)N * 4;
static constexpr size_t OFF_XT = 262144;                       // packed B, 4 MB
static constexpr size_t OFF_SP = OFF_XT + (size_t)CH * N * 2;  // 2x8192 f32
static constexpr size_t OFF_PV = OFF_SP + (size_t)NJC * N * 4; // 1x8 MB

// K1a: partial t-vectors over h-slices of 8.
__global__ __launch_bounds__(256) void k1a(
    const float* __restrict__ W, const float* __restrict__ w1,
    const float* __restrict__ w2, float* __restrict__ p1, float* __restrict__ p2)
{
    int b = blockIdx.x, c = threadIdx.x;
    float a1 = 0.f, a2 = 0.f;
#pragma unroll
    for (int hh = 0; hh < 8; ++hh) {
        int h = b * 8 + hh;
        float wv = W[h * CH + c];
        a1 = __builtin_fmaf(w1[h], wv, a1);
        a2 = __builtin_fmaf(w2[h], wv, a2);
    }
    p1[b * CH + c] = a1;
    p2[b * CH + c] = a2;
}

// K1b: fold 32 partials -> t1,t2.
__global__ __launch_bounds__(256) void k1b(
    const float* __restrict__ p1, const float* __restrict__ p2,
    float* __restrict__ t1, float* __restrict__ t2)
{
    int c = threadIdx.x;
    float a1 = 0.f, a2 = 0.f;
#pragma unroll 8
    for (int b = 0; b < 32; ++b) { a1 += p1[b * CH + c]; a2 += p2[b * CH + c]; }
    t1[c] = a1;
    t2[c] = a2;
}

// KTF: fused pack + f1/f2. inlayer [N][CH] f32 -> xtp fragment-packed bf16 and
// per-row dots f1,f2.
__global__ __launch_bounds__(256) void ktf(
    const float* __restrict__ x, const float* __restrict__ t1,
    const float* __restrict__ t2, const float* __restrict__ b1,
    const float* __restrict__ b2, unsigned short* __restrict__ xtp,
    float* __restrict__ f1, float* __restrict__ f2)
{
    __shared__ unsigned short tile[32][264];     // +8 pad
    int js32 = blockIdx.x;
    int jb = js32 * 32;
    int t = threadIdx.x;
    int lane = t & 63;
    int wv = t >> 6;
    const float4* t1v = (const float4*)t1;
    const float4* t2v = (const float4*)t2;
    float4 ta = t1v[lane], tb = t2v[lane];
    float bb1 = b1[0], bb2 = b2[0];
#pragma unroll
    for (int it = 0; it < 8; ++it) {
        int jr = it * 4 + wv;
        float4 v = *(const float4*)(x + (size_t)(jb + jr) * CH + lane * 4);
        __hip_bfloat16 h0 = __float2bfloat16(v.x);
        __hip_bfloat16 h1 = __float2bfloat16(v.y);
        __hip_bfloat16 h2 = __float2bfloat16(v.z);
        __hip_bfloat16 h3 = __float2bfloat16(v.w);
        tile[jr][lane * 4 + 0] = *(unsigned short*)&h0;
        tile[jr][lane * 4 + 1] = *(unsigned short*)&h1;
        tile[jr][lane * 4 + 2] = *(unsigned short*)&h2;
        tile[jr][lane * 4 + 3] = *(unsigned short*)&h3;
        float d1 = v.x * ta.x + v.y * ta.y + v.z * ta.z + v.w * ta.w;
        float d2 = v.x * tb.x + v.y * tb.y + v.z * tb.z + v.w * tb.w;
#pragma unroll
        for (int off = 32; off; off >>= 1) {
            d1 += __shfl_down(d1, off);
            d2 += __shfl_down(d2, off);
        }
        if (lane == 0) { f1[jb + jr] = d1 + bb1; f2[jb + jr] = d2 + bb2; }
    }
    __syncthreads();
    int r = lane & 15, q = lane >> 4;
#pragma unroll
    for (int pass = 0; pass < 4; ++pass) {
        int ct = pass * 4 + wv;
        unsigned short vs[8];
#pragma unroll
        for (int e = 0; e < 8; ++e) vs[e] = tile[q * 8 + e][ct * 16 + r];
        size_t u = ((size_t)ct * 256 + js32) * 64 + lane;
        *(ulonglong2*)(xtp + u * 8) = *(ulonglong2*)vs;
    }
}

// Raw barrier: LDS visibility only; global loads stay in flight per-wave.
#define BAR() { asm volatile("s_waitcnt lgkmcnt(0)" ::: "memory"); \
                __builtin_amdgcn_s_barrier(); }

// K34 v9: producer/consumer wave specialization.
// 1024 threads = 16 waves. Waves 0-7: consumers (MFMA + B loads only).
// Waves 8-15: producers (adj load + exp + P LDS write only).
// BM=64 rows x 4096-j chunk (NJC=2), JT=128, NT=32, grid 256 (1 block/CU).
// P double-buffered LDS, XOR-swizzled unit = row*16 + (slot ^ (row&7)).
// One barrier per tile: consumers eat P[t&1] while producers fill P[(t+1)&1].
__global__ __launch_bounds__(1024, 4) void k34_fused(
    const int* __restrict__ adj, const float* __restrict__ f1,
    const float* __restrict__ f2, const unsigned short* __restrict__ xtp,
    float* __restrict__ pv0, float* __restrict__ pvx, float* __restrict__ s_part)
{
    __shared__ __align__(16) unsigned short P[2][BM * JT];   // 2 x 16 KB
    __shared__ __align__(16) float f2s[JCW];                 // 16 KB

    const int tid = threadIdx.x;
    const int lane = tid & 63;
    const int w = tid >> 6;              // wave 0..15
    const int r = lane & 15, q = lane >> 4;
    const int bid = blockIdx.x;
    const int jc = bid & 1;              // j-chunk
    const int rb = (bid >> 1) * BM;
    const int jbase = jc * JCW;
    const bool cons = (w < 8);

    // ---- producer setup (waves 8-15): row = ptid>>3 (0..63), 16 j's at (ptid&7)*16
    const int ptid = tid - 512;
    const int prow = (ptid >> 3) & 63;
    const int pjo = (ptid & 7) * 16;
    const int* aptr = adj + (size_t)(rb + prow) * N + jbase + pjo;
    const int s0i = (ptid & 7) * 2;
    const int wu0 = prow * 16 + (s0i ^ (prow & 7));
    const int wu1 = prow * 16 + ((s0i + 1) ^ (prow & 7));
    float f1r = 0.f;
    if (!cons) f1r = f1[rb + prow];

    // ---- consumer setup (waves 0-7): wave w covers cts {w*2, w*2+1}
    const unsigned short* xb0 = xtp + (((size_t)(w * 2) * 256 + jc * (JCW / 32)) * 64 + lane) * 8;
    const unsigned short* xb1 = xtp + (((size_t)(w * 2 + 1) * 256 + jc * (JCW / 32)) * 64 + lane) * 8;

    f32x4 acc[4][2];
#pragma unroll
    for (int mt = 0; mt < 4; ++mt)
#pragma unroll
        for (int nt = 0; nt < 2; ++nt) acc[mt][nt] = (f32x4){0.f, 0.f, 0.f, 0.f};
    float s_acc = 0.f;

    int4 RA0, RA1, RA2, RA3, RB0, RB1, RB2, RB3;

#define LOAD_A(R0, R1, R2, R3, t)                                   \
    { const int4* p_ = (const int4*)(aptr + (size_t)(t) * JT);      \
      R0 = p_[0]; R1 = p_[1]; R2 = p_[2]; R3 = p_[3]; }
#define EXPW(R0, R1, R2, R3, buf, tt)                               \
    { float4 g0 = *(const float4*)(&f2s[(tt) * JT + pjo]);          \
      float4 g1 = *(const float4*)(&f2s[(tt) * JT + pjo + 4]);      \
      float4 g2 = *(const float4*)(&f2s[(tt) * JT + pjo + 8]);      \
      float4 g3 = *(const float4*)(&f2s[(tt) * JT + pjo + 12]);     \
      int av[16] = {R0.x, R0.y, R0.z, R0.w, R1.x, R1.y, R1.z, R1.w, \
                    R2.x, R2.y, R2.z, R2.w, R3.x, R3.y, R3.z, R3.w};\
      float gv[16] = {g0.x, g0.y, g0.z, g0.w, g1.x, g1.y, g1.z, g1.w,\
                      g2.x, g2.y, g2.z, g2.w, g3.x, g3.y, g3.z, g3.w};\
      bf16x8 pk0, pk1;                                              \
      _Pragma("unroll")                                             \
      for (int e = 0; e < 16; ++e) {                                \
          float t_ = f1r + gv[e];                                   \
          t_ = fmaxf(t_, 0.01f * t_);                               \
          float p_ = (av[e] > 0) ? __expf(t_) : 0.f;                \
          s_acc += p_;                                              \
          if (e < 8) pk0[e] = (__bf16)p_; else pk1[e - 8] = (__bf16)p_; \
      }                                                             \
      *reinterpret_cast<bf16x8*>(&P[buf][(size_t)wu0 * 8]) = pk0;   \
      *reinterpret_cast<bf16x8*>(&P[buf][(size_t)wu1 * 8]) = pk1; }
#define MFMA_TILE(tt, buf)                                          \
    { _Pragma("unroll")                                             \
      for (int kk = 0; kk < 4; ++kk) {                              \
          bf16x8 B0 = *(const bf16x8*)(xb0 + ((size_t)((tt) * 4 + kk) * 64) * 8); \
          bf16x8 B1 = *(const bf16x8*)(xb1 + ((size_t)((tt) * 4 + kk) * 64) * 8); \
          _Pragma("unroll")                                         \
          for (int mt = 0; mt < 4; ++mt) {                          \
              int u_ = (mt * 16 + r) * 16 + ((kk * 4 + q) ^ (r & 7)); \
              bf16x8 A = *(const bf16x8*)(&P[buf][(size_t)u_ * 8]); \
              acc[mt][0] = __builtin_amdgcn_mfma_f32_16x16x32_bf16(A, B0, acc[mt][0], 0, 0, 0); \
              acc[mt][1] = __builtin_amdgcn_mfma_f32_16x16x32_bf16(A, B1, acc[mt][1], 0, 0, 0); \
          }                                                         \
      } }

    // stage f2 chunk into LDS (all 1024 threads, 4 floats each = 4096)
    *(float4*)(&f2s[tid * 4]) = *(const float4*)(f2 + jbase + tid * 4);

    // prologue
    if (!cons) {
        LOAD_A(RA0, RA1, RA2, RA3, 0);
        LOAD_A(RB0, RB1, RB2, RB3, 1);
    }
    __syncthreads();                      // f2s staged (full drain once)
    if (!cons) EXPW(RA0, RA1, RA2, RA3, 0, 0);
    BAR();                                // P[0] ready

    for (int t = 0; t < NT; t += 2) {
        // first half: consumers eat P[0] (tile t); producers fill P[1] (tile t+1)
        if (cons) {
            MFMA_TILE(t, 0);
        } else {
            if (t + 2 < NT) LOAD_A(RA0, RA1, RA2, RA3, t + 2);
            EXPW(RB0, RB1, RB2, RB3, 1, t + 1);
        }
        BAR();
        // second half: consumers eat P[1] (tile t+1); producers fill P[0] (tile t+2)
        if (cons) {
            MFMA_TILE(t + 1, 1);
        } else {
            if (t + 3 < NT) LOAD_A(RB0, RB1, RB2, RB3, t + 3);
            if (t + 2 < NT) EXPW(RA0, RA1, RA2, RA3, 0, t + 2);
        }
        BAR();
    }

    if (!cons) {
        // row-sum partial: 8 producer threads per row (consecutive lanes)
        s_acc += __shfl_xor(s_acc, 1);
        s_acc += __shfl_xor(s_acc, 2);
        s_acc += __shfl_xor(s_acc, 4);
        if ((lane & 7) == 0) s_part[jc * N + rb + prow] = s_acc;
    } else {
        // write PV partial. D layout: col = lane&15, row = (lane>>4)*4 + reg
        float* dst = (jc == 0) ? pv0 : pvx;
#pragma unroll
        for (int mt = 0; mt < 4; ++mt)
#pragma unroll
            for (int nt = 0; nt < 2; ++nt)
#pragma unroll
                for (int reg = 0; reg < 4; ++reg) {
                    int row = rb + mt * 16 + q * 4 + reg;
                    int col = w * 32 + nt * 16 + r;
                    dst[(size_t)row * CH + col] = acc[mt][nt][reg];
                }
    }
#undef LOAD_A
#undef EXPW
#undef MFMA_TILE
}

// K5: out[i][c] = (pv0 + pvx) * inv(s0 + s1). pv0 lives in d_out.
__global__ __launch_bounds__(256) void k5_reduce(
    const float* __restrict__ pvx, const float* __restrict__ s_part,
    float* __restrict__ out)
{
    int g = blockIdx.x * 256 + threadIdx.x;      // float4 index
    int row = g >> 6;
    float s = s_part[row] + s_part[N + row];
    float inv = (s != 0.f) ? 1.0f / s : 0.f;
    float4* out4 = (float4*)out;
    const float4* p1 = (const float4*)pvx;
    float4 v = out4[g];
    float4 a = p1[g];
    v.x = (v.x + a.x) * inv;
    v.y = (v.y + a.y) * inv;
    v.z = (v.z + a.z) * inv;
    v.w = (v.w + a.w) * inv;
    out4[g] = v;
}

extern "C" void kernel_launch(void* const* d_in, const int* in_sizes, int n_in,
                              void* d_out, int out_size, void* d_ws, size_t ws_size,
                              hipStream_t stream)
{
    const float* inlayer = (const float*)d_in[0];
    const int*   adj     = (const int*)d_in[1];
    const float* W       = (const float*)d_in[2];
    const float* w1      = (const float*)d_in[3];
    const float* b1      = (const float*)d_in[4];
    const float* w2      = (const float*)d_in[5];
    const float* b2      = (const float*)d_in[6];
    float* out = (float*)d_out;

    char* ws = (char*)d_ws;
    float* p1 = (float*)(ws + OFF_P1);
    float* p2 = (float*)(ws + OFF_P2);
    float* t1 = (float*)(ws + OFF_T1);
    float* t2 = (float*)(ws + OFF_T2);
    float* f1 = (float*)(ws + OFF_F1);
    float* f2 = (float*)(ws + OFF_F2);
    unsigned short* xtp = (unsigned short*)(ws + OFF_XT);
    float* s_part = (float*)(ws + OFF_SP);
    float* pvx = (float*)(ws + OFF_PV);

    k1a<<<dim3(32), dim3(256), 0, stream>>>(W, w1, w2, p1, p2);
    k1b<<<dim3(1), dim3(256), 0, stream>>>(p1, p2, t1, t2);
    ktf<<<dim3(N / 32), dim3(256), 0, stream>>>(
        inlayer, t1, t2, b1, b2, xtp, f1, f2);
    k34_fused<<<dim3((N / BM) * NJC), dim3(1024), 0, stream>>>(
        adj, f1, f2, xtp, out, pvx, s_part);
    k5_reduce<<<dim3(N * CH / 4 / 256), dim3(256), 0, stream>>>(pvx, s_part, out);
}